// Round 17
// baseline (190.898 us; speedup 1.0000x reference)
//
#include <hip/hip_runtime.h>
#include <cstdint>
#include <cstddef>

#define B_ 16384
#define K_ 512
#define H_ 4096
#define O_ 512

typedef __attribute__((ext_vector_type(4))) float f32x4;

#define EPS_FLAG 0.75f
#define WSCALE 64.0f
#define INV2SCALE 0.03125f   /* 2/64, exact */

// ---------------------------------------------------------------------------
// Exact helpers (bitwise vs numpy reference — proven in rounds 1-16)
// ---------------------------------------------------------------------------
__device__ inline unsigned char f32_to_e4m3(float f) {
  unsigned u = __float_as_uint(f);
  unsigned char s = (unsigned char)((u >> 24) & 0x80u);
  if ((u & 0x7FFFFFFFu) == 0) return s;
  int e = (int)((u >> 23) & 0xFF) - 127;
  unsigned m = u & 0x7FFFFFu;
  if (e >= -6) {
    unsigned keep = m >> 20;
    unsigned rest = m & 0xFFFFFu;
    unsigned round = (rest > 0x80000u) || (rest == 0x80000u && (keep & 1u));
    keep += round;
    if (keep == 8u) { keep = 0u; e += 1; }
    if (e > 8) return (unsigned char)(s | 0x7Eu);  // clamp to 448 (never hit)
    return (unsigned char)(s | (unsigned)((e + 7) << 3) | keep);
  } else {
    float af = __uint_as_float(u & 0x7FFFFFFFu);
    int q = (int)rintf(af * 512.0f);   // RNE; q in 0..8 (q=8 == min normal)
    return (unsigned char)(s | (unsigned)q);
  }
}

// Fused prep: blocks [0,2048) x rows -> e4m3(x); [2048,2560) W rows ->
// e4m3(64*w); [2560,4608) transpose G. Sumsq path bitwise-proven (R3-R16).
__global__ __launch_bounds__(256) void prep_all_kernel(
    const float* __restrict__ x, const float* __restrict__ W,
    const float* __restrict__ G,
    unsigned char* __restrict__ xq8, unsigned char* __restrict__ wq8,
    float* __restrict__ xsq, float* __restrict__ wsq, float* __restrict__ GT) {
  const int bid = (int)blockIdx.x;
  const int tid = (int)threadIdx.x;

  if (bid < 2560) {
    const int isx = bid < 2048;
    const float* src = isx ? x : W;
    unsigned char* q8 = isx ? xq8 : wq8;
    float* sumsq = isx ? xsq : wsq;
    const float scale = isx ? 1.0f : WSCALE;
    const int r0 = (isx ? bid : bid - 2048) * 8;

    __shared__ float buf[8 * 512];
    #pragma unroll
    for (int it = 0; it < 4; ++it) {
      int i = tid + it * 256;
      float4 v = ((const float4*)(src + (size_t)r0 * K_))[i];
      ((float4*)buf)[i] = v;
      uchar4 h;
      h.x = f32_to_e4m3(v.x * scale);
      h.y = f32_to_e4m3(v.y * scale);
      h.z = f32_to_e4m3(v.z * scale);
      h.w = f32_to_e4m3(v.w * scale);
      ((uchar4*)(q8 + (size_t)r0 * K_))[i] = h;
    }
    __syncthreads();

    const int row = tid >> 5, l = tid & 31, blk = l >> 3, j = l & 7;
    const float* p = buf + row * 512 + blk * 128;
    float r = __fmul_rn(p[j], p[j]);
    #pragma unroll
    for (int i = 8; i < 128; i += 8) r = __fadd_rn(r, __fmul_rn(p[i + j], p[i + j]));
    r = __fadd_rn(r, __shfl_xor(r, 1));
    r = __fadd_rn(r, __shfl_xor(r, 2));
    r = __fadd_rn(r, __shfl_xor(r, 4));
    r = __fadd_rn(r, __shfl_xor(r, 8));
    r = __fadd_rn(r, __shfl_xor(r, 16));
    if (l == 0) sumsq[r0 + row] = r;
  } else {
    __shared__ float t[32][33];
    const int bid2 = bid - 2560;
    const int h0 = (bid2 & 127) * 32, o0 = (bid2 >> 7) * 32;
    const int tx = tid & 31, ty = tid >> 5;
    for (int i = ty; i < 32; i += 8)
      t[i][tx] = G[(size_t)(o0 + i) * H_ + h0 + tx];
    __syncthreads();
    for (int i = ty; i < 32; i += 8)
      GT[(size_t)(h0 + i) * O_ + o0 + tx] = t[tx][i];
  }
}

__device__ float np_pairwise_sumsq512(const float* __restrict__ a) {
  float s[4];
  #pragma unroll
  for (int blk = 0; blk < 4; ++blk) {
    const float* p = a + blk * 128;
    float r[8];
    #pragma unroll
    for (int j = 0; j < 8; ++j) r[j] = __fmul_rn(p[j], p[j]);
    for (int i = 8; i < 128; i += 8) {
      #pragma unroll
      for (int j = 0; j < 8; ++j) r[j] = __fadd_rn(r[j], __fmul_rn(p[i + j], p[i + j]));
    }
    s[blk] = __fadd_rn(__fadd_rn(__fadd_rn(r[0], r[1]), __fadd_rn(r[2], r[3])),
                       __fadd_rn(__fadd_rn(r[4], r[5]), __fadd_rn(r[6], r[7])));
  }
  return __fadd_rn(__fadd_rn(s[0], s[1]), __fadd_rn(s[2], s[3]));
}

__global__ void rowsumsq_kernel(const float* __restrict__ src, float* __restrict__ dst,
                                int nrows) {
  int r = blockIdx.x * blockDim.x + threadIdx.x;
  if (r < nrows) dst[r] = np_pairwise_sumsq512(src + (size_t)r * K_);
}

__global__ void transposeG_kernel(const float* __restrict__ G, float* __restrict__ GT) {
  __shared__ float t[32][33];
  int h0 = blockIdx.x * 32, o0 = blockIdx.y * 32;
  for (int i = threadIdx.y; i < 32; i += 8)
    t[i][threadIdx.x] = G[(size_t)(o0 + i) * H_ + h0 + threadIdx.x];
  __syncthreads();
  for (int i = threadIdx.y; i < 32; i += 8)
    GT[(size_t)(h0 + i) * O_ + o0 + threadIdx.x] = t[threadIdx.x][i];
}

// ---------------------------------------------------------------------------
// Phase 1 (fp8): 256x256 tile, 8 waves (2Mx4N, per-wave 128x64), BK=128 fp8,
// 4 K-tiles, 2-phase double buffer (R7/R16-proven sync). LDS traffic halves
// vs bf16 (R16 was LDS-traffic-bound at MfmaUtil 33%). Swizzle: 128B rows =
// 8x16B slots, bank-aligned (row-term mod 32 = 0); slot16 ^= row&7 on both
// sides (pre-swizzled global source, linear gl_lds dest, swizzled b64 read)
// -> <=2-way (free). W pre-scaled by 64 (all normal-range e4m3); epilogue
// un-scales via exact 2/64.
// ---------------------------------------------------------------------------
__device__ inline void stage_panel_fp8(char* lds_panel, const unsigned char* __restrict__ src,
                                       int rowbase, int kt, int tid) {
  // [256][128]fp8 panel = 32KB = 2048 16B-units; 512 threads x 4 units
  #pragma unroll
  for (int j = 0; j < 4; ++j) {
    int u = j * 512 + tid;
    int row = u >> 3, slot = u & 7;
    const char* g = (const char*)src + (size_t)(rowbase + row) * K_ + kt * 128 +
                    ((slot ^ (row & 7)) * 16);
    __builtin_amdgcn_global_load_lds((const __attribute__((address_space(1))) void*)g,
                                     (__attribute__((address_space(3))) void*)(lds_panel + u * 16),
                                     16, 0, 0);
  }
}

__global__ __launch_bounds__(512, 2) void phase1_mfma_kernel(
    const unsigned char* __restrict__ xq8, const unsigned char* __restrict__ wq8,
    const float* __restrict__ wsq, const float* __restrict__ xsq,
    float* __restrict__ gmin16 /*[B_][256]*/,
    unsigned short* __restrict__ mk16 /*[B_][256]*/) {
  // K-loop: 2 buffers x (A 32KB + B 32KB) = 128KB
  // epilogue union: T 8 x [16][129] f32 (66048B); EpiF [256][16] f32 @66048;
  //                 EpiM [256][16] u16 @82432
  __shared__ __align__(16) char smem[131072];
  const int tid = (int)threadIdx.x;
  const int wid = tid >> 6, lane = tid & 63;
  const int wr = wid >> 2, wc = wid & 3;       // per-wave 128 rows x 64 cols
  const int cb = blockIdx.y;
  const int row0 = blockIdx.x * 256, col0 = cb * 256;

  f32x4 acc[8][4];
  #pragma unroll
  for (int i = 0; i < 8; ++i)
    #pragma unroll
    for (int j = 0; j < 4; ++j) acc[i][j] = (f32x4){0.f, 0.f, 0.f, 0.f};

  const int r16 = lane & 15, r7 = lane & 7, sg = lane >> 4;
  // byte offset within a 128B row for k-subtile ks: ((2ks+(sg>>1))^r7)*16+(sg&1)*8
  int offK[4];
  #pragma unroll
  for (int ks = 0; ks < 4; ++ks)
    offK[ks] = (((2 * ks + (sg >> 1)) ^ r7) & 7) * 16 + (sg & 1) * 8;
  const int arowb = wr * 128 + r16;
  const int browb = wc * 64 + r16;

  stage_panel_fp8(smem, xq8, row0, 0, tid);
  stage_panel_fp8(smem + 32768, wq8, col0, 0, tid);
  __syncthreads();

  int buf = 0;
  for (int kt = 0; kt < 4; ++kt) {
    if (kt < 3) {
      stage_panel_fp8(smem + (buf ^ 1) * 65536, xq8, row0, kt + 1, tid);
      stage_panel_fp8(smem + (buf ^ 1) * 65536 + 32768, wq8, col0, kt + 1, tid);
    }
    const char* A = smem + buf * 65536;
    const char* Bm = smem + buf * 65536 + 32768;
    #pragma unroll
    for (int ks = 0; ks < 4; ++ks) {
      const int ofk = offK[ks];
      long long ah[8];
      #pragma unroll
      for (int mf = 0; mf < 8; ++mf)
        ah[mf] = *(const long long*)(A + (arowb + mf * 16) * 128 + ofk);
      #pragma unroll
      for (int nf = 0; nf < 4; ++nf) {
        long long bh = *(const long long*)(Bm + (browb + nf * 16) * 128 + ofk);
        #pragma unroll
        for (int mf = 0; mf < 8; ++mf)
          acc[mf][nf] = __builtin_amdgcn_mfma_f32_16x16x32_fp8_fp8(ah[mf], bh, acc[mf][nf], 0, 0, 0);
      }
    }
    __syncthreads();   // drains next stage + protects buffer reuse
    buf ^= 1;
  }

  // ---- epilogue (R13/R16-verified structure) ----
  // s_approx = wsq[col] - (2/64)*acc. D layout: col=lane&15, row=(lane>>4)*4+reg.
  float* T = (float*)smem + wid * (16 * 129);
  float* EpiF = (float*)(smem + 66048);
  unsigned short* EpiM = (unsigned short*)(smem + 82432);

  const float xq0 = xsq[row0 + wr * 128 + lane];
  const float xq1 = xsq[row0 + wr * 128 + 64 + lane];
  const int c = r16;

  #pragma unroll
  for (int nf = 0; nf < 4; ++nf) {
    float wq = wsq[col0 + wc * 64 + nf * 16 + c];
    #pragma unroll
    for (int mf = 0; mf < 8; ++mf)
      #pragma unroll
      for (int r = 0; r < 4; ++r)
        T[c * 129 + mf * 16 + sg * 4 + r] = wq - INV2SCALE * acc[mf][nf][r];
    asm volatile("s_waitcnt lgkmcnt(0)" ::: "memory");
    __builtin_amdgcn_sched_barrier(0);
    #pragma unroll
    for (int half = 0; half < 2; ++half) {
      int lrow = lane + half * 64;
      float xq = half ? xq1 : xq0;
      float v[16];
      #pragma unroll
      for (int c2 = 0; c2 < 16; ++c2) v[c2] = T[c2 * 129 + lrow];
      float mn = v[0];
      #pragma unroll
      for (int c2 = 1; c2 < 16; ++c2) mn = fminf(mn, v[c2]);
      unsigned msk = 0;
      #pragma unroll
      for (int c2 = 0; c2 < 16; ++c2)
        if ((v[c2] <= mn + EPS_FLAG) || (v[c2] + xq <= EPS_FLAG)) msk |= 1u << c2;
      EpiF[(wr * 128 + lrow) * 16 + wc * 4 + nf] = mn;
      EpiM[(wr * 128 + lrow) * 16 + wc * 4 + nf] = (unsigned short)msk;
    }
  }
  __syncthreads();

  {
    int row = tid >> 1, hf = tid & 1;
    const float* fr = EpiF + row * 16 + hf * 8;
    size_t gbase = (size_t)(row0 + row) * 256 + cb * 16 + hf * 8;
    *(float4*)&gmin16[gbase] = *(const float4*)fr;
    *(float4*)&gmin16[gbase + 4] = *(const float4*)(fr + 4);
    uint4 mv = *(const uint4*)(EpiM + row * 16 + hf * 8);
    *(uint4*)&mk16[gbase] = mv;
  }
}

// ---------------------------------------------------------------------------
// Phase 2 (R15-proven): 16 rows/block, block-wide candidate compaction.
// ---------------------------------------------------------------------------
#define P2_ROWS 16
#define P2_CAP 2048

__global__ __launch_bounds__(256) void phase2_block_kernel(
    const float* __restrict__ gm /*[B_][256]*/,
    const unsigned short* __restrict__ mk /*[B_][256]*/,
    const float* __restrict__ x, const float* __restrict__ W,
    const float* __restrict__ xsq, const float* __restrict__ wsq,
    const float* __restrict__ GT, float* __restrict__ out) {
  __shared__ float xls[P2_ROWS * 516];
  __shared__ unsigned short clist[P2_CAP];
  __shared__ unsigned long long bestkey[P2_ROWS];
  __shared__ int ncand;
  const int tid = (int)threadIdx.x;
  const int r = tid >> 4, t16 = tid & 15;
  const int b0 = blockIdx.x * P2_ROWS;
  const int b = b0 + r;

  if (tid < P2_ROWS) bestkey[tid] = 0xFFFFFFFFFFFFFFFFULL;
  if (tid == 0) ncand = 0;

  #pragma unroll
  for (int it = 0; it < 8; ++it) {
    int idx = tid + it * 256;
    int xr = idx >> 7, xw = idx & 127;
    float4 v = ((const float4*)(x + (size_t)(b0 + xr) * K_))[xw];
    *(float4*)&xls[xr * 516 + xw * 4] = v;
  }

  float gv[16];
  #pragma unroll
  for (int j = 0; j < 4; ++j) {
    float4 v = *(const float4*)(gm + (size_t)b * 256 + t16 * 16 + j * 4);
    gv[j * 4 + 0] = v.x;
    gv[j * 4 + 1] = v.y;
    gv[j * 4 + 2] = v.z;
    gv[j * 4 + 3] = v.w;
  }
  unsigned short mv[16];
  #pragma unroll
  for (int j = 0; j < 2; ++j) {
    uint4 u = *(const uint4*)(mk + (size_t)b * 256 + t16 * 16 + j * 8);
    mv[j * 8 + 0] = (unsigned short)(u.x & 0xFFFF);
    mv[j * 8 + 1] = (unsigned short)(u.x >> 16);
    mv[j * 8 + 2] = (unsigned short)(u.y & 0xFFFF);
    mv[j * 8 + 3] = (unsigned short)(u.y >> 16);
    mv[j * 8 + 4] = (unsigned short)(u.z & 0xFFFF);
    mv[j * 8 + 5] = (unsigned short)(u.z >> 16);
    mv[j * 8 + 6] = (unsigned short)(u.w & 0xFFFF);
    mv[j * 8 + 7] = (unsigned short)(u.w >> 16);
  }

  float mn = gv[0];
  #pragma unroll
  for (int j = 1; j < 16; ++j) mn = fminf(mn, gv[j]);
  #pragma unroll
  for (int off = 1; off < 16; off <<= 1) mn = fminf(mn, __shfl_xor(mn, off, 16));
  const float xq = xsq[b];
  const float thr = mn + EPS_FLAG;
  __syncthreads();

  #pragma unroll
  for (int j = 0; j < 16; ++j) {
    float v = gv[j];
    if ((v <= thr) || (v + xq <= EPS_FLAG)) {
      int g = t16 * 16 + j;
      unsigned mbits = mv[j];
      while (mbits) {
        int bit = __ffs(mbits) - 1;
        mbits &= mbits - 1;
        int slot = atomicAdd(&ncand, 1);
        if (slot < P2_CAP)
          clist[slot] = (unsigned short)((r << 12) | (g * 16 + bit));
      }
    }
  }
  __syncthreads();

  int total = ncand;
  if (total <= P2_CAP) {
    for (int i = tid; i < total; i += 256) {
      unsigned e = clist[i];
      int rr = (int)(e >> 12);
      int col = (int)(e & 0xFFF);
      const float* xr = xls + rr * 516;
      const float4* wrow = (const float4*)(W + (size_t)col * K_);
      float acc = 0.0f;
      #pragma unroll 8
      for (int kq = 0; kq < K_ / 4; ++kq) {
        float4 xv = *(const float4*)&xr[kq * 4];
        float4 wv = wrow[kq];
        acc = fmaf(xv.x, wv.x, acc);
        acc = fmaf(xv.y, wv.y, acc);
        acc = fmaf(xv.z, wv.z, acc);
        acc = fmaf(xv.w, wv.w, acc);
      }
      float xqr = xsq[b0 + rr];
      float t2 = xqr - 2.0f * acc;
      float sq = t2 + wsq[col];
      float d = sqrtf(fmaxf(sq, 0.0f));
      unsigned long long key =
          ((unsigned long long)__float_as_uint(d) << 32) | (unsigned)col;
      atomicMin(&bestkey[rr], key);
    }
  } else {
    for (int cc = t16; cc < H_; cc += 16) {
      int g = cc >> 4;
      float gvv = gm[(size_t)b * 256 + g];
      if ((gvv <= thr || gvv + xq <= EPS_FLAG) &&
          ((mk[(size_t)b * 256 + g] >> (cc & 15)) & 1)) {
        const float* xr = xls + r * 516;
        const float4* wrow = (const float4*)(W + (size_t)cc * K_);
        float acc = 0.0f;
        #pragma unroll 8
        for (int kq = 0; kq < K_ / 4; ++kq) {
          float4 xv = *(const float4*)&xr[kq * 4];
          float4 wv = wrow[kq];
          acc = fmaf(xv.x, wv.x, acc);
          acc = fmaf(xv.y, wv.y, acc);
          acc = fmaf(xv.z, wv.z, acc);
          acc = fmaf(xv.w, wv.w, acc);
        }
        float t2 = xq - 2.0f * acc;
        float sq = t2 + wsq[cc];
        float d = sqrtf(fmaxf(sq, 0.0f));
        unsigned long long key =
            ((unsigned long long)__float_as_uint(d) << 32) | (unsigned)cc;
        atomicMin(&bestkey[r], key);
      }
    }
  }
  __syncthreads();

  {
    const unsigned h = (unsigned)(bestkey[r] & 0xFFFFFFFFULL);
    const float4* gsrc = (const float4*)(GT + (size_t)h * O_);
    float4* gdst = (float4*)(out + (size_t)b * O_);
    #pragma unroll
    for (int j = 0; j < 8; ++j) gdst[j * 16 + t16] = gsrc[j * 16 + t16];
    if (t16 == 0) out[(size_t)B_ * O_ + b] = (float)h;
  }
}

// ---------------------------------------------------------------------------
// Round-1 fallback (exact f32 vector GEMM + argmin) — used only if ws too small
// ---------------------------------------------------------------------------
#define BM 128
#define BN 128
#define BKK 16

__global__ void init_keys_kernel(unsigned long long* __restrict__ keys) {
  int i = blockIdx.x * blockDim.x + threadIdx.x;
  if (i < B_) keys[i] = 0xFFFFFFFFFFFFFFFFULL;
}

__global__ __launch_bounds__(256) void dist_argmin_kernel(
    const float* __restrict__ x, const float* __restrict__ W,
    const float* __restrict__ xsq, const float* __restrict__ wsq,
    unsigned long long* __restrict__ keys) {
  __shared__ float xs[BKK][BM + 4];
  __shared__ float wsh[BKK][BN + 4];
  const int row0 = blockIdx.x * BM;
  const int col0 = blockIdx.y * BN;
  const int tid = (int)threadIdx.x;
  const int tx = tid & 15, ty = tid >> 4;

  float acc[8][8];
  #pragma unroll
  for (int i = 0; i < 8; ++i)
    #pragma unroll
    for (int j = 0; j < 8; ++j) acc[i][j] = 0.0f;

  for (int kt = 0; kt < K_; kt += BKK) {
    #pragma unroll
    for (int l = 0; l < 2; ++l) {
      int e = tid + l * 256;
      int r = e >> 2, kq = e & 3;
      float4 v = *(const float4*)(x + (size_t)(row0 + r) * K_ + kt + kq * 4);
      xs[kq * 4 + 0][r] = v.x;
      xs[kq * 4 + 1][r] = v.y;
      xs[kq * 4 + 2][r] = v.z;
      xs[kq * 4 + 3][r] = v.w;
      float4 u = *(const float4*)(W + (size_t)(col0 + r) * K_ + kt + kq * 4);
      wsh[kq * 4 + 0][r] = u.x;
      wsh[kq * 4 + 1][r] = u.y;
      wsh[kq * 4 + 2][r] = u.z;
      wsh[kq * 4 + 3][r] = u.w;
    }
    __syncthreads();
    #pragma unroll
    for (int k = 0; k < BKK; ++k) {
      float4 a0 = *(const float4*)&xs[k][ty * 4];
      float4 a1 = *(const float4*)&xs[k][ty * 4 + 64];
      float4 b0 = *(const float4*)&wsh[k][tx * 4];
      float4 b1 = *(const float4*)&wsh[k][tx * 4 + 64];
      float ar[8] = {a0.x, a0.y, a0.z, a0.w, a1.x, a1.y, a1.z, a1.w};
      float br[8] = {b0.x, b0.y, b0.z, b0.w, b1.x, b1.y, b1.z, b1.w};
      #pragma unroll
      for (int i = 0; i < 8; ++i)
        #pragma unroll
        for (int j = 0; j < 8; ++j)
          acc[i][j] = fmaf(ar[i], br[j], acc[i][j]);
    }
    __syncthreads();
  }

  float xv[8], wv[8];
  int rowidx[8], colidx[8];
  #pragma unroll
  for (int i = 0; i < 8; ++i) {
    rowidx[i] = row0 + ty * 4 + (i & 3) + (i >> 2) * 64;
    xv[i] = xsq[rowidx[i]];
  }
  #pragma unroll
  for (int j = 0; j < 8; ++j) {
    colidx[j] = col0 + tx * 4 + (j & 3) + (j >> 2) * 64;
    wv[j] = wsq[colidx[j]];
  }
  #pragma unroll
  for (int i = 0; i < 8; ++i) {
    unsigned long long best = 0xFFFFFFFFFFFFFFFFULL;
    #pragma unroll
    for (int j = 0; j < 8; ++j) {
      float t2 = xv[i] - 2.0f * acc[i][j];
      float sq = t2 + wv[j];
      float d = sqrtf(fmaxf(sq, 0.0f));
      unsigned long long key =
          ((unsigned long long)__float_as_uint(d) << 32) | (unsigned)colidx[j];
      best = key < best ? key : best;
    }
    #pragma unroll
    for (int off = 1; off < 16; off <<= 1) {
      unsigned long long o = __shfl_xor(best, off, 16);
      best = o < best ? o : best;
    }
    if (tx == 0) atomicMin(&keys[rowidx[i]], best);
  }
}

__global__ void finalize_kernel(const unsigned long long* __restrict__ keys,
                                const float* __restrict__ GT,
                                const float* __restrict__ G,
                                float* __restrict__ out, int useGT) {
  int b = blockIdx.x;
  unsigned h = (unsigned)(keys[b] & 0xFFFFFFFFULL);
  if (threadIdx.x == 0) out[(size_t)B_ * O_ + b] = (float)h;
  if (useGT) {
    const float4* src = (const float4*)(GT + (size_t)h * O_);
    float4* dst = (float4*)(out + (size_t)b * O_);
    for (int i = threadIdx.x; i < O_ / 4; i += blockDim.x) dst[i] = src[i];
  } else {
    for (int o = threadIdx.x; o < O_; o += blockDim.x)
      out[(size_t)b * O_ + o] = G[(size_t)o * H_ + h];
  }
}

// ---------------------------------------------------------------------------
extern "C" void kernel_launch(void* const* d_in, const int* in_sizes, int n_in,
                              void* d_out, int out_size, void* d_ws, size_t ws_size,
                              hipStream_t stream) {
  const float* x = (const float*)d_in[0];
  const float* W = (const float*)d_in[1];
  const float* G = (const float*)d_in[2];
  float* out = (float*)d_out;
  char* ws = (char*)d_ws;

  size_t o_xsq  = 0;                                  // 64 KB
  size_t o_wsq  = o_xsq + 65536;                      // 16 KB
  size_t o_xq8  = o_wsq + 16384;                      // 8 MB
  size_t o_wq8  = o_xq8 + (size_t)B_ * K_;            // 2 MB
  size_t o_gm   = o_wq8 + (size_t)H_ * K_;            // 16 MB
  size_t o_mk   = o_gm + (size_t)B_ * 256 * 4;        // 8 MB
  size_t o_gt   = o_mk + (size_t)B_ * 256 * 2;        // 8 MB
  size_t need   = o_gt + (size_t)H_ * O_ * 4;

  if (ws_size >= need) {
    float* xsq = (float*)(ws + o_xsq);
    float* wsq = (float*)(ws + o_wsq);
    unsigned char* xq8 = (unsigned char*)(ws + o_xq8);
    unsigned char* wq8 = (unsigned char*)(ws + o_wq8);
    float* gm = (float*)(ws + o_gm);
    unsigned short* mk = (unsigned short*)(ws + o_mk);
    float* GT = (float*)(ws + o_gt);

    hipLaunchKernelGGL(prep_all_kernel, dim3(2048 + 512 + 2048), dim3(256), 0, stream,
                       x, W, G, xq8, wq8, xsq, wsq, GT);
    hipLaunchKernelGGL(phase1_mfma_kernel, dim3(B_ / 256, H_ / 256), dim3(512), 0, stream,
                       xq8, wq8, wsq, xsq, gm, mk);
    hipLaunchKernelGGL(phase2_block_kernel, dim3(B_ / P2_ROWS), dim3(256), 0, stream,
                       gm, mk, x, W, xsq, wsq, GT, out);
    return;
  }

  // Fallback: round-1 exact path
  unsigned long long* keys = (unsigned long long*)ws;
  float* xsq = (float*)(ws + 131072);
  float* wsq = (float*)(ws + 131072 + 65536);
  float* GT = (float*)(ws + 131072 + 65536 + 16384);
  size_t base = 131072 + 65536 + 16384;
  int useGT = ws_size >= base + (size_t)H_ * O_ * 4 ? 1 : 0;

  hipLaunchKernelGGL(init_keys_kernel, dim3(B_ / 256), dim3(256), 0, stream, keys);
  hipLaunchKernelGGL(rowsumsq_kernel, dim3(B_ / 256), dim3(256), 0, stream, x, xsq, B_);
  hipLaunchKernelGGL(rowsumsq_kernel, dim3(H_ / 256), dim3(256), 0, stream, W, wsq, H_);
  if (useGT)
    hipLaunchKernelGGL(transposeG_kernel, dim3(H_ / 32, O_ / 32), dim3(32, 8), 0, stream,
                       G, GT);
  hipLaunchKernelGGL(dist_argmin_kernel, dim3(B_ / BM, H_ / BN), dim3(256), 0, stream,
                     x, W, xsq, wsq, keys);
  hipLaunchKernelGGL(finalize_kernel, dim3(B_), dim3(128), 0, stream, keys, GT, G, out,
                     useGT);
}

// Round 18
// 132.336 us; speedup vs baseline: 1.4425x; 1.4425x over previous
//
#include <hip/hip_runtime.h>
#include <cstdint>
#include <cstddef>

#define B_ 16384
#define K_ 512
#define H_ 4096
#define O_ 512

typedef __attribute__((ext_vector_type(4))) float f32x4;
typedef __attribute__((ext_vector_type(8))) short bf16x8;

#define EPS_FLAG 0.125f

// ---------------------------------------------------------------------------
// Exact helpers (bitwise vs numpy reference — proven in rounds 1-16)
// ---------------------------------------------------------------------------
__device__ inline unsigned short f32_to_bf16_rne(float f) {
  unsigned u = __float_as_uint(f);
  unsigned r = (u + 0x7fffu + ((u >> 16) & 1u)) >> 16;
  return (unsigned short)r;
}

__device__ float np_pairwise_sumsq512(const float* __restrict__ a) {
  float s[4];
  #pragma unroll
  for (int blk = 0; blk < 4; ++blk) {
    const float* p = a + blk * 128;
    float r[8];
    #pragma unroll
    for (int j = 0; j < 8; ++j) r[j] = __fmul_rn(p[j], p[j]);
    for (int i = 8; i < 128; i += 8) {
      #pragma unroll
      for (int j = 0; j < 8; ++j) r[j] = __fadd_rn(r[j], __fmul_rn(p[i + j], p[i + j]));
    }
    s[blk] = __fadd_rn(__fadd_rn(__fadd_rn(r[0], r[1]), __fadd_rn(r[2], r[3])),
                       __fadd_rn(__fadd_rn(r[4], r[5]), __fadd_rn(r[6], r[7])));
  }
  return __fadd_rn(__fadd_rn(s[0], s[1]), __fadd_rn(s[2], s[3]));
}

// Fused prep:
//  blocks [0,1024):      x -> fragment-packed bf16 (xpk) + xsq (16 rows/blk)
//  blocks [1024,1536):   W -> row-major bf16 (whi) + wsq (8 rows/blk)
//  blocks [1536,3584):   transpose G -> GT
// xpk layout: chunk c = RG*16+kg (RG=row/16, kg=k/32), 1KB each:
//   bytes ((c*64)+lane)*16 hold x[RG*16+(lane&15)][kg*32+(lane>>4)*8 + 0..7]
// = exactly one wave's MFMA A-fragment, contiguous.
__global__ __launch_bounds__(256) void prep_all_kernel(
    const float* __restrict__ x, const float* __restrict__ W,
    const float* __restrict__ G,
    unsigned short* __restrict__ xpk, unsigned short* __restrict__ whi,
    float* __restrict__ xsq, float* __restrict__ wsq, float* __restrict__ GT) {
  const int bid = (int)blockIdx.x;
  const int tid = (int)threadIdx.x;
  __shared__ float buf[16 * 516];   // 33 KB; also aliased by other branches

  if (bid < 1024) {
    const int r0 = bid * 16;
    // stage 16 rows (coalesced)
    #pragma unroll
    for (int it = 0; it < 8; ++it) {
      int idx = tid + it * 256;          // 0..2047 float4s
      int xr = idx >> 7, xw = idx & 127;
      float4 v = ((const float4*)(x + (size_t)(r0 + xr) * K_))[xw];
      *(float4*)&buf[xr * 516 + xw * 4] = v;
    }
    __syncthreads();

    // sumsq: proven 32-lane pairwise chain, two 8-row halves
    {
      const int l = tid & 31, blk = l >> 3, j = l & 7;
      #pragma unroll
      for (int hf = 0; hf < 2; ++hf) {
        int row = (tid >> 5) + hf * 8;
        const float* p = buf + row * 516 + blk * 128;
        float r = __fmul_rn(p[j], p[j]);
        #pragma unroll
        for (int i = 8; i < 128; i += 8) r = __fadd_rn(r, __fmul_rn(p[i + j], p[i + j]));
        r = __fadd_rn(r, __shfl_xor(r, 1));
        r = __fadd_rn(r, __shfl_xor(r, 2));
        r = __fadd_rn(r, __shfl_xor(r, 4));
        r = __fadd_rn(r, __shfl_xor(r, 8));
        r = __fadd_rn(r, __shfl_xor(r, 16));
        if (l == 0) xsq[r0 + row] = r;
      }
    }

    // packed write: s = tid + i*256 -> chunk ks=s>>6, lane l=s&63 (coalesced)
    #pragma unroll
    for (int i = 0; i < 4; ++i) {
      int s = tid + i * 256;
      int ks = s >> 6, l = s & 63;
      const float* p = buf + (l & 15) * 516 + ks * 32 + (l >> 4) * 8;
      ushort4 lo, hi;
      lo.x = f32_to_bf16_rne(p[0]);
      lo.y = f32_to_bf16_rne(p[1]);
      lo.z = f32_to_bf16_rne(p[2]);
      lo.w = f32_to_bf16_rne(p[3]);
      hi.x = f32_to_bf16_rne(p[4]);
      hi.y = f32_to_bf16_rne(p[5]);
      hi.z = f32_to_bf16_rne(p[6]);
      hi.w = f32_to_bf16_rne(p[7]);
      ushort4* dst = (ushort4*)((char*)xpk + ((size_t)bid * 1024 + s) * 16);
      dst[0] = lo;
      dst[1] = hi;
    }
  } else if (bid < 1536) {
    const int r0 = (bid - 1024) * 8;
    #pragma unroll
    for (int it = 0; it < 4; ++it) {
      int i = tid + it * 256;
      float4 v = ((const float4*)(W + (size_t)r0 * K_))[i];
      ((float4*)buf)[i] = v;
      ushort4 h;
      h.x = f32_to_bf16_rne(v.x);
      h.y = f32_to_bf16_rne(v.y);
      h.z = f32_to_bf16_rne(v.z);
      h.w = f32_to_bf16_rne(v.w);
      ((ushort4*)(whi + (size_t)r0 * K_))[i] = h;
    }
    __syncthreads();

    const int row = tid >> 5, l = tid & 31, blk = l >> 3, j = l & 7;
    const float* p = buf + row * 512 + blk * 128;
    float r = __fmul_rn(p[j], p[j]);
    #pragma unroll
    for (int i = 8; i < 128; i += 8) r = __fadd_rn(r, __fmul_rn(p[i + j], p[i + j]));
    r = __fadd_rn(r, __shfl_xor(r, 1));
    r = __fadd_rn(r, __shfl_xor(r, 2));
    r = __fadd_rn(r, __shfl_xor(r, 4));
    r = __fadd_rn(r, __shfl_xor(r, 8));
    r = __fadd_rn(r, __shfl_xor(r, 16));
    if (l == 0) wsq[r0 + row] = r;
  } else {
    float(*t)[33] = (float(*)[33])buf;
    const int bid2 = bid - 1536;
    const int h0 = (bid2 & 127) * 32, o0 = (bid2 >> 7) * 32;
    const int tx = tid & 31, ty = tid >> 5;
    for (int i = ty; i < 32; i += 8)
      t[i][tx] = G[(size_t)(o0 + i) * H_ + h0 + tx];
    __syncthreads();
    for (int i = ty; i < 32; i += 8)
      GT[(size_t)(h0 + i) * O_ + o0 + tx] = t[tx][i];
  }
}

__global__ void rowsumsq_kernel(const float* __restrict__ src, float* __restrict__ dst,
                                int nrows) {
  int r = blockIdx.x * blockDim.x + threadIdx.x;
  if (r < nrows) dst[r] = np_pairwise_sumsq512(src + (size_t)r * K_);
}

__global__ void transposeG_kernel(const float* __restrict__ G, float* __restrict__ GT) {
  __shared__ float t[32][33];
  int h0 = blockIdx.x * 32, o0 = blockIdx.y * 32;
  for (int i = threadIdx.y; i < 32; i += 8)
    t[i][threadIdx.x] = G[(size_t)(o0 + i) * H_ + h0 + threadIdx.x];
  __syncthreads();
  for (int i = threadIdx.y; i < 32; i += 8)
    GT[(size_t)(h0 + i) * O_ + o0 + threadIdx.x] = t[threadIdx.x][i];
}

// ---------------------------------------------------------------------------
// Phase 1: 256x256 tile, 8 waves (2Mx4N, per-wave 128x64), BK=64.
// A: fragment-packed GLOBAL loads (coalesced 1KB/wave, L1/L2-served; 4 waves
// share each slice) — zero LDS involvement. B: LDS double-buffer with XOR-8
// swizzle (R12/R16-proven). LDS traffic per K-tile drops 256KB -> 96KB; A's
// 128KB rides the parallel vector path. Same (kt,ks) accumulate order ->
// bitwise-identical results.
// ---------------------------------------------------------------------------
__device__ inline void stage_panelB(char* lds_panel, const unsigned short* __restrict__ src,
                                    int rowbase, int kt, int tid) {
  // [256][64]bf16 panel = 32KB = 2048 16B-units; 512 threads x 4 units
  #pragma unroll
  for (int j = 0; j < 4; ++j) {
    int u = j * 512 + tid;
    int row = u >> 3, slot = u & 7;
    const char* g = (const char*)src + (size_t)(rowbase + row) * (K_ * 2) + kt * 128 +
                    ((slot ^ (row & 7)) * 16);
    __builtin_amdgcn_global_load_lds((const __attribute__((address_space(1))) void*)g,
                                     (__attribute__((address_space(3))) void*)(lds_panel + u * 16),
                                     16, 0, 0);
  }
}

__global__ __launch_bounds__(512) void phase1_mfma_kernel(
    const unsigned short* __restrict__ xpk, const unsigned short* __restrict__ whi,
    const float* __restrict__ wsq, const float* __restrict__ xsq,
    float* __restrict__ gmin16 /*[B_][256]*/,
    unsigned short* __restrict__ mk16 /*[B_][256]*/) {
  // B dbuf: 2 x 32KB = 65536
  // epilogue union: T 8 x [16][129] f32 (66048B); EpiF [256][16] f32 @66048;
  //                 EpiM [256][16] u16 @82432 (total 90624)
  __shared__ __align__(16) char smem[90624];
  const int tid = (int)threadIdx.x;
  const int wid = tid >> 6, lane = tid & 63;
  const int wr = wid >> 2, wc = wid & 3;       // per-wave 128 rows x 64 cols
  const int cb = blockIdx.y;
  const int row0 = blockIdx.x * 256, col0 = cb * 256;

  f32x4 acc[8][4];
  #pragma unroll
  for (int i = 0; i < 8; ++i)
    #pragma unroll
    for (int j = 0; j < 4; ++j) acc[i][j] = (f32x4){0.f, 0.f, 0.f, 0.f};

  const int r16 = lane & 15, r7 = lane & 7, sg = lane >> 4;
  const int offK0 = ((sg ^ r7) & 7) * 16;
  const int offK1 = (((4 + sg) ^ r7) & 7) * 16;
  const int browb = wc * 64 + r16;
  // A packed base: RG = row0/16 + wr*8 + mf; chunk byte = (RG*16+kg)*1024
  const char* apk = (const char*)xpk + ((size_t)(blockIdx.x * 16 + wr * 8) * 16 ) * 1024 + lane * 16;

  stage_panelB(smem, whi, col0, 0, tid);
  __syncthreads();

  int buf = 0;
  for (int kt = 0; kt < 8; ++kt) {
    if (kt < 7)
      stage_panelB(smem + (buf ^ 1) * 32768, whi, col0, kt + 1, tid);

    // A fragments for this K-tile: 16 coalesced global 16B loads
    bf16x8 ah[2][8];
    #pragma unroll
    for (int ks = 0; ks < 2; ++ks)
      #pragma unroll
      for (int mf = 0; mf < 8; ++mf)
        ah[ks][mf] = *(const bf16x8*)(apk + ((size_t)mf * 16 + (kt * 2 + ks)) * 1024);

    const char* Bm = smem + buf * 32768;
    #pragma unroll
    for (int ks = 0; ks < 2; ++ks) {
      const int offK = ks ? offK1 : offK0;
      #pragma unroll
      for (int nf = 0; nf < 4; ++nf) {
        bf16x8 bh = *(const bf16x8*)(Bm + (browb + nf * 16) * 128 + offK);
        #pragma unroll
        for (int mf = 0; mf < 8; ++mf)
          acc[mf][nf] = __builtin_amdgcn_mfma_f32_16x16x32_bf16(ah[ks][mf], bh, acc[mf][nf], 0, 0, 0);
      }
    }
    __syncthreads();   // drains B stage + protects buffer reuse (R7-safe)
    buf ^= 1;
  }

  // ---- epilogue (R13/R16-verified) ----
  float* T = (float*)smem + wid * (16 * 129);
  float* EpiF = (float*)(smem + 66048);
  unsigned short* EpiM = (unsigned short*)(smem + 82432);

  const float xq0 = xsq[row0 + wr * 128 + lane];
  const float xq1 = xsq[row0 + wr * 128 + 64 + lane];
  const int c = r16;

  #pragma unroll
  for (int nf = 0; nf < 4; ++nf) {
    float wq = wsq[col0 + wc * 64 + nf * 16 + c];
    #pragma unroll
    for (int mf = 0; mf < 8; ++mf)
      #pragma unroll
      for (int r = 0; r < 4; ++r)
        T[c * 129 + mf * 16 + sg * 4 + r] = wq - 2.0f * acc[mf][nf][r];
    asm volatile("s_waitcnt lgkmcnt(0)" ::: "memory");
    __builtin_amdgcn_sched_barrier(0);
    #pragma unroll
    for (int half = 0; half < 2; ++half) {
      int lrow = lane + half * 64;
      float xq = half ? xq1 : xq0;
      float v[16];
      #pragma unroll
      for (int c2 = 0; c2 < 16; ++c2) v[c2] = T[c2 * 129 + lrow];
      float mn = v[0];
      #pragma unroll
      for (int c2 = 1; c2 < 16; ++c2) mn = fminf(mn, v[c2]);
      unsigned msk = 0;
      #pragma unroll
      for (int c2 = 0; c2 < 16; ++c2)
        if ((v[c2] <= mn + EPS_FLAG) || (v[c2] + xq <= EPS_FLAG)) msk |= 1u << c2;
      EpiF[(wr * 128 + lrow) * 16 + wc * 4 + nf] = mn;
      EpiM[(wr * 128 + lrow) * 16 + wc * 4 + nf] = (unsigned short)msk;
    }
  }
  __syncthreads();

  {
    int row = tid >> 1, hf = tid & 1;
    const float* fr = EpiF + row * 16 + hf * 8;
    size_t gbase = (size_t)(row0 + row) * 256 + cb * 16 + hf * 8;
    *(float4*)&gmin16[gbase] = *(const float4*)fr;
    *(float4*)&gmin16[gbase + 4] = *(const float4*)(fr + 4);
    uint4 mv = *(const uint4*)(EpiM + row * 16 + hf * 8);
    *(uint4*)&mk16[gbase] = mv;
  }
}

// ---------------------------------------------------------------------------
// Phase 2 (R15-proven): 16 rows/block, block-wide candidate compaction.
// ---------------------------------------------------------------------------
#define P2_ROWS 16
#define P2_CAP 2048

__global__ __launch_bounds__(256) void phase2_block_kernel(
    const float* __restrict__ gm /*[B_][256]*/,
    const unsigned short* __restrict__ mk /*[B_][256]*/,
    const float* __restrict__ x, const float* __restrict__ W,
    const float* __restrict__ xsq, const float* __restrict__ wsq,
    const float* __restrict__ GT, float* __restrict__ out) {
  __shared__ float xls[P2_ROWS * 516];
  __shared__ unsigned short clist[P2_CAP];
  __shared__ unsigned long long bestkey[P2_ROWS];
  __shared__ int ncand;
  const int tid = (int)threadIdx.x;
  const int r = tid >> 4, t16 = tid & 15;
  const int b0 = blockIdx.x * P2_ROWS;
  const int b = b0 + r;

  if (tid < P2_ROWS) bestkey[tid] = 0xFFFFFFFFFFFFFFFFULL;
  if (tid == 0) ncand = 0;

  #pragma unroll
  for (int it = 0; it < 8; ++it) {
    int idx = tid + it * 256;
    int xr = idx >> 7, xw = idx & 127;
    float4 v = ((const float4*)(x + (size_t)(b0 + xr) * K_))[xw];
    *(float4*)&xls[xr * 516 + xw * 4] = v;
  }

  float gv[16];
  #pragma unroll
  for (int j = 0; j < 4; ++j) {
    float4 v = *(const float4*)(gm + (size_t)b * 256 + t16 * 16 + j * 4);
    gv[j * 4 + 0] = v.x;
    gv[j * 4 + 1] = v.y;
    gv[j * 4 + 2] = v.z;
    gv[j * 4 + 3] = v.w;
  }
  unsigned short mv[16];
  #pragma unroll
  for (int j = 0; j < 2; ++j) {
    uint4 u = *(const uint4*)(mk + (size_t)b * 256 + t16 * 16 + j * 8);
    mv[j * 8 + 0] = (unsigned short)(u.x & 0xFFFF);
    mv[j * 8 + 1] = (unsigned short)(u.x >> 16);
    mv[j * 8 + 2] = (unsigned short)(u.y & 0xFFFF);
    mv[j * 8 + 3] = (unsigned short)(u.y >> 16);
    mv[j * 8 + 4] = (unsigned short)(u.z & 0xFFFF);
    mv[j * 8 + 5] = (unsigned short)(u.z >> 16);
    mv[j * 8 + 6] = (unsigned short)(u.w & 0xFFFF);
    mv[j * 8 + 7] = (unsigned short)(u.w >> 16);
  }

  float mn = gv[0];
  #pragma unroll
  for (int j = 1; j < 16; ++j) mn = fminf(mn, gv[j]);
  #pragma unroll
  for (int off = 1; off < 16; off <<= 1) mn = fminf(mn, __shfl_xor(mn, off, 16));
  const float xq = xsq[b];
  const float thr = mn + EPS_FLAG;
  __syncthreads();

  #pragma unroll
  for (int j = 0; j < 16; ++j) {
    float v = gv[j];
    if ((v <= thr) || (v + xq <= EPS_FLAG)) {
      int g = t16 * 16 + j;
      unsigned mbits = mv[j];
      while (mbits) {
        int bit = __ffs(mbits) - 1;
        mbits &= mbits - 1;
        int slot = atomicAdd(&ncand, 1);
        if (slot < P2_CAP)
          clist[slot] = (unsigned short)((r << 12) | (g * 16 + bit));
      }
    }
  }
  __syncthreads();

  int total = ncand;
  if (total <= P2_CAP) {
    for (int i = tid; i < total; i += 256) {
      unsigned e = clist[i];
      int rr = (int)(e >> 12);
      int col = (int)(e & 0xFFF);
      const float* xr = xls + rr * 516;
      const float4* wrow = (const float4*)(W + (size_t)col * K_);
      float acc = 0.0f;
      #pragma unroll 8
      for (int kq = 0; kq < K_ / 4; ++kq) {
        float4 xv = *(const float4*)&xr[kq * 4];
        float4 wv = wrow[kq];
        acc = fmaf(xv.x, wv.x, acc);
        acc = fmaf(xv.y, wv.y, acc);
        acc = fmaf(xv.z, wv.z, acc);
        acc = fmaf(xv.w, wv.w, acc);
      }
      float xqr = xsq[b0 + rr];
      float t2 = xqr - 2.0f * acc;
      float sq = t2 + wsq[col];
      float d = sqrtf(fmaxf(sq, 0.0f));
      unsigned long long key =
          ((unsigned long long)__float_as_uint(d) << 32) | (unsigned)col;
      atomicMin(&bestkey[rr], key);
    }
  } else {
    for (int cc = t16; cc < H_; cc += 16) {
      int g = cc >> 4;
      float gvv = gm[(size_t)b * 256 + g];
      if ((gvv <= thr || gvv + xq <= EPS_FLAG) &&
          ((mk[(size_t)b * 256 + g] >> (cc & 15)) & 1)) {
        const float* xr = xls + r * 516;
        const float4* wrow = (const float4*)(W + (size_t)cc * K_);
        float acc = 0.0f;
        #pragma unroll 8
        for (int kq = 0; kq < K_ / 4; ++kq) {
          float4 xv = *(const float4*)&xr[kq * 4];
          float4 wv = wrow[kq];
          acc = fmaf(xv.x, wv.x, acc);
          acc = fmaf(xv.y, wv.y, acc);
          acc = fmaf(xv.z, wv.z, acc);
          acc = fmaf(xv.w, wv.w, acc);
        }
        float t2 = xq - 2.0f * acc;
        float sq = t2 + wsq[cc];
        float d = sqrtf(fmaxf(sq, 0.0f));
        unsigned long long key =
            ((unsigned long long)__float_as_uint(d) << 32) | (unsigned)cc;
        atomicMin(&bestkey[r], key);
      }
    }
  }
  __syncthreads();

  {
    const unsigned h = (unsigned)(bestkey[r] & 0xFFFFFFFFULL);
    const float4* gsrc = (const float4*)(GT + (size_t)h * O_);
    float4* gdst = (float4*)(out + (size_t)b * O_);
    #pragma unroll
    for (int j = 0; j < 8; ++j) gdst[j * 16 + t16] = gsrc[j * 16 + t16];
    if (t16 == 0) out[(size_t)B_ * O_ + b] = (float)h;
  }
}

// ---------------------------------------------------------------------------
// Round-1 fallback (exact f32 vector GEMM + argmin) — used only if ws too small
// ---------------------------------------------------------------------------
#define BM 128
#define BN 128
#define BKK 16

__global__ void init_keys_kernel(unsigned long long* __restrict__ keys) {
  int i = blockIdx.x * blockDim.x + threadIdx.x;
  if (i < B_) keys[i] = 0xFFFFFFFFFFFFFFFFULL;
}

__global__ __launch_bounds__(256) void dist_argmin_kernel(
    const float* __restrict__ x, const float* __restrict__ W,
    const float* __restrict__ xsq, const float* __restrict__ wsq,
    unsigned long long* __restrict__ keys) {
  __shared__ float xs[BKK][BM + 4];
  __shared__ float wsh[BKK][BN + 4];
  const int row0 = blockIdx.x * BM;
  const int col0 = blockIdx.y * BN;
  const int tid = (int)threadIdx.x;
  const int tx = tid & 15, ty = tid >> 4;

  float acc[8][8];
  #pragma unroll
  for (int i = 0; i < 8; ++i)
    #pragma unroll
    for (int j = 0; j < 8; ++j) acc[i][j] = 0.0f;

  for (int kt = 0; kt < K_; kt += BKK) {
    #pragma unroll
    for (int l = 0; l < 2; ++l) {
      int e = tid + l * 256;
      int r = e >> 2, kq = e & 3;
      float4 v = *(const float4*)(x + (size_t)(row0 + r) * K_ + kt + kq * 4);
      xs[kq * 4 + 0][r] = v.x;
      xs[kq * 4 + 1][r] = v.y;
      xs[kq * 4 + 2][r] = v.z;
      xs[kq * 4 + 3][r] = v.w;
      float4 u = *(const float4*)(W + (size_t)(col0 + r) * K_ + kt + kq * 4);
      wsh[kq * 4 + 0][r] = u.x;
      wsh[kq * 4 + 1][r] = u.y;
      wsh[kq * 4 + 2][r] = u.z;
      wsh[kq * 4 + 3][r] = u.w;
    }
    __syncthreads();
    #pragma unroll
    for (int k = 0; k < BKK; ++k) {
      float4 a0 = *(const float4*)&xs[k][ty * 4];
      float4 a1 = *(const float4*)&xs[k][ty * 4 + 64];
      float4 b0 = *(const float4*)&wsh[k][tx * 4];
      float4 b1 = *(const float4*)&wsh[k][tx * 4 + 64];
      float ar[8] = {a0.x, a0.y, a0.z, a0.w, a1.x, a1.y, a1.z, a1.w};
      float br[8] = {b0.x, b0.y, b0.z, b0.w, b1.x, b1.y, b1.z, b1.w};
      #pragma unroll
      for (int i = 0; i < 8; ++i)
        #pragma unroll
        for (int j = 0; j < 8; ++j)
          acc[i][j] = fmaf(ar[i], br[j], acc[i][j]);
    }
    __syncthreads();
  }

  float xv[8], wv[8];
  int rowidx[8], colidx[8];
  #pragma unroll
  for (int i = 0; i < 8; ++i) {
    rowidx[i] = row0 + ty * 4 + (i & 3) + (i >> 2) * 64;
    xv[i] = xsq[rowidx[i]];
  }
  #pragma unroll
  for (int j = 0; j < 8; ++j) {
    colidx[j] = col0 + tx * 4 + (j & 3) + (j >> 2) * 64;
    wv[j] = wsq[colidx[j]];
  }
  #pragma unroll
  for (int i = 0; i < 8; ++i) {
    unsigned long long best = 0xFFFFFFFFFFFFFFFFULL;
    #pragma unroll
    for (int j = 0; j < 8; ++j) {
      float t2 = xv[i] - 2.0f * acc[i][j];
      float sq = t2 + wv[j];
      float d = sqrtf(fmaxf(sq, 0.0f));
      unsigned long long key =
          ((unsigned long long)__float_as_uint(d) << 32) | (unsigned)colidx[j];
      best = key < best ? key : best;
    }
    #pragma unroll
    for (int off = 1; off < 16; off <<= 1) {
      unsigned long long o = __shfl_xor(best, off, 16);
      best = o < best ? o : best;
    }
    if (tx == 0) atomicMin(&keys[rowidx[i]], best);
  }
}

__global__ void finalize_kernel(const unsigned long long* __restrict__ keys,
                                const float* __restrict__ GT,
                                const float* __restrict__ G,
                                float* __restrict__ out, int useGT) {
  int b = blockIdx.x;
  unsigned h = (unsigned)(keys[b] & 0xFFFFFFFFULL);
  if (threadIdx.x == 0) out[(size_t)B_ * O_ + b] = (float)h;
  if (useGT) {
    const float4* src = (const float4*)(GT + (size_t)h * O_);
    float4* dst = (float4*)(out + (size_t)b * O_);
    for (int i = threadIdx.x; i < O_ / 4; i += blockDim.x) dst[i] = src[i];
  } else {
    for (int o = threadIdx.x; o < O_; o += blockDim.x)
      out[(size_t)b * O_ + o] = G[(size_t)o * H_ + h];
  }
}

// ---------------------------------------------------------------------------
extern "C" void kernel_launch(void* const* d_in, const int* in_sizes, int n_in,
                              void* d_out, int out_size, void* d_ws, size_t ws_size,
                              hipStream_t stream) {
  const float* x = (const float*)d_in[0];
  const float* W = (const float*)d_in[1];
  const float* G = (const float*)d_in[2];
  float* out = (float*)d_out;
  char* ws = (char*)d_ws;

  size_t o_xsq  = 0;                                  // 64 KB
  size_t o_wsq  = o_xsq + 65536;                      // 16 KB
  size_t o_xpk  = o_wsq + 16384;                      // 16 MB (fragment-packed)
  size_t o_whi  = o_xpk + (size_t)B_ * K_ * 2;        // 4 MB
  size_t o_gm   = o_whi + (size_t)H_ * K_ * 2;        // 16 MB
  size_t o_mk   = o_gm + (size_t)B_ * 256 * 4;        // 8 MB
  size_t o_gt   = o_mk + (size_t)B_ * 256 * 2;        // 8 MB
  size_t need   = o_gt + (size_t)H_ * O_ * 4;

  if (ws_size >= need) {
    float* xsq = (float*)(ws + o_xsq);
    float* wsq = (float*)(ws + o_wsq);
    unsigned short* xpk = (unsigned short*)(ws + o_xpk);
    unsigned short* whi = (unsigned short*)(ws + o_whi);
    float* gm = (float*)(ws + o_gm);
    unsigned short* mk = (unsigned short*)(ws + o_mk);
    float* GT = (float*)(ws + o_gt);

    hipLaunchKernelGGL(prep_all_kernel, dim3(1024 + 512 + 2048), dim3(256), 0, stream,
                       x, W, G, xpk, whi, xsq, wsq, GT);
    hipLaunchKernelGGL(phase1_mfma_kernel, dim3(B_ / 256, H_ / 256), dim3(512), 0, stream,
                       xpk, whi, wsq, xsq, gm, mk);
    hipLaunchKernelGGL(phase2_block_kernel, dim3(B_ / P2_ROWS), dim3(256), 0, stream,
                       gm, mk, x, W, xsq, wsq, GT, out);
    return;
  }

  // Fallback: round-1 exact path
  unsigned long long* keys = (unsigned long long*)ws;
  float* xsq = (float*)(ws + 131072);
  float* wsq = (float*)(ws + 131072 + 65536);
  float* GT = (float*)(ws + 131072 + 65536 + 16384);
  size_t base = 131072 + 65536 + 16384;
  int useGT = ws_size >= base + (size_t)H_ * O_ * 4 ? 1 : 0;

  hipLaunchKernelGGL(init_keys_kernel, dim3(B_ / 256), dim3(256), 0, stream, keys);
  hipLaunchKernelGGL(rowsumsq_kernel, dim3(B_ / 256), dim3(256), 0, stream, x, xsq, B_);
  hipLaunchKernelGGL(rowsumsq_kernel, dim3(H_ / 256), dim3(256), 0, stream, W, wsq, H_);
  if (useGT)
    hipLaunchKernelGGL(transposeG_kernel, dim3(H_ / 32, O_ / 32), dim3(32, 8), 0, stream,
                       G, GT);
  hipLaunchKernelGGL(dist_argmin_kernel, dim3(B_ / BM, H_ / BN), dim3(256), 0, stream,
                     x, W, xsq, wsq, keys);
  hipLaunchKernelGGL(finalize_kernel, dim3(B_), dim3(128), 0, stream, keys, GT, G, out,
                     useGT);
}

// Round 19
// 119.352 us; speedup vs baseline: 1.5994x; 1.1088x over previous
//
#include <hip/hip_runtime.h>
#include <cstdint>
#include <cstddef>

#define B_ 16384
#define K_ 512
#define H_ 4096
#define O_ 512

typedef __attribute__((ext_vector_type(4))) float f32x4;
typedef __attribute__((ext_vector_type(8))) short bf16x8;

#define EPS_FLAG 0.125f

// ---------------------------------------------------------------------------
// Exact helpers (bitwise vs numpy reference — proven in rounds 1-16)
// ---------------------------------------------------------------------------
__device__ inline unsigned short f32_to_bf16_rne(float f) {
  unsigned u = __float_as_uint(f);
  unsigned r = (u + 0x7fffu + ((u >> 16) & 1u)) >> 16;
  return (unsigned short)r;
}

__device__ float np_pairwise_sumsq512(const float* __restrict__ a) {
  float s[4];
  #pragma unroll
  for (int blk = 0; blk < 4; ++blk) {
    const float* p = a + blk * 128;
    float r[8];
    #pragma unroll
    for (int j = 0; j < 8; ++j) r[j] = __fmul_rn(p[j], p[j]);
    for (int i = 8; i < 128; i += 8) {
      #pragma unroll
      for (int j = 0; j < 8; ++j) r[j] = __fadd_rn(r[j], __fmul_rn(p[i + j], p[i + j]));
    }
    s[blk] = __fadd_rn(__fadd_rn(__fadd_rn(r[0], r[1]), __fadd_rn(r[2], r[3])),
                       __fadd_rn(__fadd_rn(r[4], r[5]), __fadd_rn(r[6], r[7])));
  }
  return __fadd_rn(__fadd_rn(s[0], s[1]), __fadd_rn(s[2], s[3]));
}

// Fused prep: blocks [0,2048) prep x rows; [2048,2560) prep W rows;
// [2560,4608) transpose G. All sub-kernels proven in rounds 3-16.
__global__ __launch_bounds__(256) void prep_all_kernel(
    const float* __restrict__ x, const float* __restrict__ W,
    const float* __restrict__ G,
    unsigned short* __restrict__ xhi, unsigned short* __restrict__ whi,
    float* __restrict__ xsq, float* __restrict__ wsq, float* __restrict__ GT) {
  const int bid = (int)blockIdx.x;
  const int tid = (int)threadIdx.x;

  if (bid < 2560) {
    const float* src = bid < 2048 ? x : W;
    unsigned short* hi = bid < 2048 ? xhi : whi;
    float* sumsq = bid < 2048 ? xsq : wsq;
    const int r0 = (bid < 2048 ? bid : bid - 2048) * 8;

    __shared__ float buf[8 * 512];
    #pragma unroll
    for (int it = 0; it < 4; ++it) {
      int i = tid + it * 256;
      float4 v = ((const float4*)(src + (size_t)r0 * K_))[i];
      ((float4*)buf)[i] = v;
      ushort4 h;
      h.x = f32_to_bf16_rne(v.x);
      h.y = f32_to_bf16_rne(v.y);
      h.z = f32_to_bf16_rne(v.z);
      h.w = f32_to_bf16_rne(v.w);
      ((ushort4*)(hi + (size_t)r0 * K_))[i] = h;
    }
    __syncthreads();

    const int row = tid >> 5, l = tid & 31, blk = l >> 3, j = l & 7;
    const float* p = buf + row * 512 + blk * 128;
    float r = __fmul_rn(p[j], p[j]);
    #pragma unroll
    for (int i = 8; i < 128; i += 8) r = __fadd_rn(r, __fmul_rn(p[i + j], p[i + j]));
    r = __fadd_rn(r, __shfl_xor(r, 1));
    r = __fadd_rn(r, __shfl_xor(r, 2));
    r = __fadd_rn(r, __shfl_xor(r, 4));
    r = __fadd_rn(r, __shfl_xor(r, 8));
    r = __fadd_rn(r, __shfl_xor(r, 16));
    if (l == 0) sumsq[r0 + row] = r;
  } else {
    __shared__ float t[32][33];
    const int bid2 = bid - 2560;
    const int h0 = (bid2 & 127) * 32, o0 = (bid2 >> 7) * 32;
    const int tx = tid & 31, ty = tid >> 5;
    for (int i = ty; i < 32; i += 8)
      t[i][tx] = G[(size_t)(o0 + i) * H_ + h0 + tx];
    __syncthreads();
    for (int i = ty; i < 32; i += 8)
      GT[(size_t)(h0 + i) * O_ + o0 + tx] = t[tx][i];
  }
}

__global__ void rowsumsq_kernel(const float* __restrict__ src, float* __restrict__ dst,
                                int nrows) {
  int r = blockIdx.x * blockDim.x + threadIdx.x;
  if (r < nrows) dst[r] = np_pairwise_sumsq512(src + (size_t)r * K_);
}

__global__ void transposeG_kernel(const float* __restrict__ G, float* __restrict__ GT) {
  __shared__ float t[32][33];
  int h0 = blockIdx.x * 32, o0 = blockIdx.y * 32;
  for (int i = threadIdx.y; i < 32; i += 8)
    t[i][threadIdx.x] = G[(size_t)(o0 + i) * H_ + h0 + threadIdx.x];
  __syncthreads();
  for (int i = threadIdx.y; i < 32; i += 8)
    GT[(size_t)(h0 + i) * O_ + o0 + threadIdx.x] = t[threadIdx.x][i];
}

// ---------------------------------------------------------------------------
// Phase 1 (R16-proven, 90.4us): 256x256 tile, 8 waves (2Mx4N, per-wave
// 128x64 output), BK=64, XOR-8 swizzle (conflict-free), plain 2-phase
// double buffer. At the 2-phase structural ceiling (763 TF effective).
// ---------------------------------------------------------------------------
__device__ inline void stage_panel256(char* lds_panel, const unsigned short* __restrict__ src,
                                      int rowbase, int kt, int tid) {
  #pragma unroll
  for (int j = 0; j < 4; ++j) {
    int u = j * 512 + tid;
    int row = u >> 3, slot = u & 7;
    const char* g = (const char*)src + (size_t)(rowbase + row) * (K_ * 2) + kt * 128 +
                    ((slot ^ (row & 7)) * 16);
    __builtin_amdgcn_global_load_lds((const __attribute__((address_space(1))) void*)g,
                                     (__attribute__((address_space(3))) void*)(lds_panel + u * 16),
                                     16, 0, 0);
  }
}

__global__ __launch_bounds__(512, 2) void phase1_mfma_kernel(
    const unsigned short* __restrict__ xhi, const unsigned short* __restrict__ whi,
    const float* __restrict__ wsq, const float* __restrict__ xsq,
    float* __restrict__ gmin16 /*[B_][256]*/,
    unsigned short* __restrict__ mk16 /*[B_][256]*/) {
  __shared__ __align__(16) char smem[131072];
  const int tid = (int)threadIdx.x;
  const int wid = tid >> 6, lane = tid & 63;
  const int wr = wid >> 2, wc = wid & 3;
  const int cb = blockIdx.y;
  const int row0 = blockIdx.x * 256, col0 = cb * 256;

  f32x4 acc[8][4];
  #pragma unroll
  for (int i = 0; i < 8; ++i)
    #pragma unroll
    for (int j = 0; j < 4; ++j) acc[i][j] = (f32x4){0.f, 0.f, 0.f, 0.f};

  const int r16 = lane & 15, r7 = lane & 7, sg = lane >> 4;
  const int offK0 = ((sg ^ r7) & 7) * 16;
  const int offK1 = (((4 + sg) ^ r7) & 7) * 16;
  const int arowb = wr * 128 + r16;
  const int browb = wc * 64 + r16;

  stage_panel256(smem, xhi, row0, 0, tid);
  stage_panel256(smem + 32768, whi, col0, 0, tid);
  __syncthreads();

  int buf = 0;
  for (int kt = 0; kt < 8; ++kt) {
    if (kt < 7) {
      stage_panel256(smem + (buf ^ 1) * 65536, xhi, row0, kt + 1, tid);
      stage_panel256(smem + (buf ^ 1) * 65536 + 32768, whi, col0, kt + 1, tid);
    }
    const char* A = smem + buf * 65536;
    const char* Bm = smem + buf * 65536 + 32768;
    #pragma unroll
    for (int ks = 0; ks < 2; ++ks) {
      const int offK = ks ? offK1 : offK0;
      bf16x8 ah[8];
      #pragma unroll
      for (int mf = 0; mf < 8; ++mf)
        ah[mf] = *(const bf16x8*)(A + (arowb + mf * 16) * 128 + offK);
      #pragma unroll
      for (int nf = 0; nf < 4; ++nf) {
        bf16x8 bh = *(const bf16x8*)(Bm + (browb + nf * 16) * 128 + offK);
        #pragma unroll
        for (int mf = 0; mf < 8; ++mf)
          acc[mf][nf] = __builtin_amdgcn_mfma_f32_16x16x32_bf16(ah[mf], bh, acc[mf][nf], 0, 0, 0);
      }
    }
    __syncthreads();
    buf ^= 1;
  }

  // ---- epilogue (R13/R16-verified) ----
  float* T = (float*)smem + wid * (16 * 129);
  float* EpiF = (float*)(smem + 66048);
  unsigned short* EpiM = (unsigned short*)(smem + 82432);

  const float xq0 = xsq[row0 + wr * 128 + lane];
  const float xq1 = xsq[row0 + wr * 128 + 64 + lane];
  const int c = r16;

  #pragma unroll
  for (int nf = 0; nf < 4; ++nf) {
    float wq = wsq[col0 + wc * 64 + nf * 16 + c];
    #pragma unroll
    for (int mf = 0; mf < 8; ++mf)
      #pragma unroll
      for (int r = 0; r < 4; ++r)
        T[c * 129 + mf * 16 + sg * 4 + r] = wq - 2.0f * acc[mf][nf][r];
    asm volatile("s_waitcnt lgkmcnt(0)" ::: "memory");
    __builtin_amdgcn_sched_barrier(0);
    #pragma unroll
    for (int half = 0; half < 2; ++half) {
      int lrow = lane + half * 64;
      float xq = half ? xq1 : xq0;
      float v[16];
      #pragma unroll
      for (int c2 = 0; c2 < 16; ++c2) v[c2] = T[c2 * 129 + lrow];
      float mn = v[0];
      #pragma unroll
      for (int c2 = 1; c2 < 16; ++c2) mn = fminf(mn, v[c2]);
      unsigned msk = 0;
      #pragma unroll
      for (int c2 = 0; c2 < 16; ++c2)
        if ((v[c2] <= mn + EPS_FLAG) || (v[c2] + xq <= EPS_FLAG)) msk |= 1u << c2;
      EpiF[(wr * 128 + lrow) * 16 + wc * 4 + nf] = mn;
      EpiM[(wr * 128 + lrow) * 16 + wc * 4 + nf] = (unsigned short)msk;
    }
  }
  __syncthreads();

  {
    int row = tid >> 1, hf = tid & 1;
    const float* fr = EpiF + row * 16 + hf * 8;
    size_t gbase = (size_t)(row0 + row) * 256 + cb * 16 + hf * 8;
    *(float4*)&gmin16[gbase] = *(const float4*)fr;
    *(float4*)&gmin16[gbase + 4] = *(const float4*)(fr + 4);
    uint4 mv = *(const uint4*)(EpiM + row * 16 + hf * 8);
    *(uint4*)&mk16[gbase] = mv;
  }
}

// ---------------------------------------------------------------------------
// Phase 2 (R15-proven): 16 rows/block, block-wide candidate compaction.
// ---------------------------------------------------------------------------
#define P2_ROWS 16
#define P2_CAP 2048

__global__ __launch_bounds__(256) void phase2_block_kernel(
    const float* __restrict__ gm /*[B_][256]*/,
    const unsigned short* __restrict__ mk /*[B_][256]*/,
    const float* __restrict__ x, const float* __restrict__ W,
    const float* __restrict__ xsq, const float* __restrict__ wsq,
    const float* __restrict__ GT, float* __restrict__ out) {
  __shared__ float xls[P2_ROWS * 516];
  __shared__ unsigned short clist[P2_CAP];
  __shared__ unsigned long long bestkey[P2_ROWS];
  __shared__ int ncand;
  const int tid = (int)threadIdx.x;
  const int r = tid >> 4, t16 = tid & 15;
  const int b0 = blockIdx.x * P2_ROWS;
  const int b = b0 + r;

  if (tid < P2_ROWS) bestkey[tid] = 0xFFFFFFFFFFFFFFFFULL;
  if (tid == 0) ncand = 0;

  #pragma unroll
  for (int it = 0; it < 8; ++it) {
    int idx = tid + it * 256;
    int xr = idx >> 7, xw = idx & 127;
    float4 v = ((const float4*)(x + (size_t)(b0 + xr) * K_))[xw];
    *(float4*)&xls[xr * 516 + xw * 4] = v;
  }

  float gv[16];
  #pragma unroll
  for (int j = 0; j < 4; ++j) {
    float4 v = *(const float4*)(gm + (size_t)b * 256 + t16 * 16 + j * 4);
    gv[j * 4 + 0] = v.x;
    gv[j * 4 + 1] = v.y;
    gv[j * 4 + 2] = v.z;
    gv[j * 4 + 3] = v.w;
  }
  unsigned short mv[16];
  #pragma unroll
  for (int j = 0; j < 2; ++j) {
    uint4 u = *(const uint4*)(mk + (size_t)b * 256 + t16 * 16 + j * 8);
    mv[j * 8 + 0] = (unsigned short)(u.x & 0xFFFF);
    mv[j * 8 + 1] = (unsigned short)(u.x >> 16);
    mv[j * 8 + 2] = (unsigned short)(u.y & 0xFFFF);
    mv[j * 8 + 3] = (unsigned short)(u.y >> 16);
    mv[j * 8 + 4] = (unsigned short)(u.z & 0xFFFF);
    mv[j * 8 + 5] = (unsigned short)(u.z >> 16);
    mv[j * 8 + 6] = (unsigned short)(u.w & 0xFFFF);
    mv[j * 8 + 7] = (unsigned short)(u.w >> 16);
  }

  float mn = gv[0];
  #pragma unroll
  for (int j = 1; j < 16; ++j) mn = fminf(mn, gv[j]);
  #pragma unroll
  for (int off = 1; off < 16; off <<= 1) mn = fminf(mn, __shfl_xor(mn, off, 16));
  const float xq = xsq[b];
  const float thr = mn + EPS_FLAG;
  __syncthreads();

  #pragma unroll
  for (int j = 0; j < 16; ++j) {
    float v = gv[j];
    if ((v <= thr) || (v + xq <= EPS_FLAG)) {
      int g = t16 * 16 + j;
      unsigned mbits = mv[j];
      while (mbits) {
        int bit = __ffs(mbits) - 1;
        mbits &= mbits - 1;
        int slot = atomicAdd(&ncand, 1);
        if (slot < P2_CAP)
          clist[slot] = (unsigned short)((r << 12) | (g * 16 + bit));
      }
    }
  }
  __syncthreads();

  int total = ncand;
  if (total <= P2_CAP) {
    for (int i = tid; i < total; i += 256) {
      unsigned e = clist[i];
      int rr = (int)(e >> 12);
      int col = (int)(e & 0xFFF);
      const float* xr = xls + rr * 516;
      const float4* wrow = (const float4*)(W + (size_t)col * K_);
      float acc = 0.0f;
      #pragma unroll 8
      for (int kq = 0; kq < K_ / 4; ++kq) {
        float4 xv = *(const float4*)&xr[kq * 4];
        float4 wv = wrow[kq];
        acc = fmaf(xv.x, wv.x, acc);
        acc = fmaf(xv.y, wv.y, acc);
        acc = fmaf(xv.z, wv.z, acc);
        acc = fmaf(xv.w, wv.w, acc);
      }
      float xqr = xsq[b0 + rr];
      float t2 = xqr - 2.0f * acc;
      float sq = t2 + wsq[col];
      float d = sqrtf(fmaxf(sq, 0.0f));
      unsigned long long key =
          ((unsigned long long)__float_as_uint(d) << 32) | (unsigned)col;
      atomicMin(&bestkey[rr], key);
    }
  } else {
    for (int cc = t16; cc < H_; cc += 16) {
      int g = cc >> 4;
      float gvv = gm[(size_t)b * 256 + g];
      if ((gvv <= thr || gvv + xq <= EPS_FLAG) &&
          ((mk[(size_t)b * 256 + g] >> (cc & 15)) & 1)) {
        const float* xr = xls + r * 516;
        const float4* wrow = (const float4*)(W + (size_t)cc * K_);
        float acc = 0.0f;
        #pragma unroll 8
        for (int kq = 0; kq < K_ / 4; ++kq) {
          float4 xv = *(const float4*)&xr[kq * 4];
          float4 wv = wrow[kq];
          acc = fmaf(xv.x, wv.x, acc);
          acc = fmaf(xv.y, wv.y, acc);
          acc = fmaf(xv.z, wv.z, acc);
          acc = fmaf(xv.w, wv.w, acc);
        }
        float t2 = xq - 2.0f * acc;
        float sq = t2 + wsq[cc];
        float d = sqrtf(fmaxf(sq, 0.0f));
        unsigned long long key =
            ((unsigned long long)__float_as_uint(d) << 32) | (unsigned)cc;
        atomicMin(&bestkey[r], key);
      }
    }
  }
  __syncthreads();

  {
    const unsigned h = (unsigned)(bestkey[r] & 0xFFFFFFFFULL);
    const float4* gsrc = (const float4*)(GT + (size_t)h * O_);
    float4* gdst = (float4*)(out + (size_t)b * O_);
    #pragma unroll
    for (int j = 0; j < 8; ++j) gdst[j * 16 + t16] = gsrc[j * 16 + t16];
    if (t16 == 0) out[(size_t)B_ * O_ + b] = (float)h;
  }
}

// ---------------------------------------------------------------------------
// Round-1 fallback (exact f32 vector GEMM + argmin) — used only if ws too small
// ---------------------------------------------------------------------------
#define BM 128
#define BN 128
#define BKK 16

__global__ void init_keys_kernel(unsigned long long* __restrict__ keys) {
  int i = blockIdx.x * blockDim.x + threadIdx.x;
  if (i < B_) keys[i] = 0xFFFFFFFFFFFFFFFFULL;
}

__global__ __launch_bounds__(256) void dist_argmin_kernel(
    const float* __restrict__ x, const float* __restrict__ W,
    const float* __restrict__ xsq, const float* __restrict__ wsq,
    unsigned long long* __restrict__ keys) {
  __shared__ float xs[BKK][BM + 4];
  __shared__ float wsh[BKK][BN + 4];
  const int row0 = blockIdx.x * BM;
  const int col0 = blockIdx.y * BN;
  const int tid = (int)threadIdx.x;
  const int tx = tid & 15, ty = tid >> 4;

  float acc[8][8];
  #pragma unroll
  for (int i = 0; i < 8; ++i)
    #pragma unroll
    for (int j = 0; j < 8; ++j) acc[i][j] = 0.0f;

  for (int kt = 0; kt < K_; kt += BKK) {
    #pragma unroll
    for (int l = 0; l < 2; ++l) {
      int e = tid + l * 256;
      int r = e >> 2, kq = e & 3;
      float4 v = *(const float4*)(x + (size_t)(row0 + r) * K_ + kt + kq * 4);
      xs[kq * 4 + 0][r] = v.x;
      xs[kq * 4 + 1][r] = v.y;
      xs[kq * 4 + 2][r] = v.z;
      xs[kq * 4 + 3][r] = v.w;
      float4 u = *(const float4*)(W + (size_t)(col0 + r) * K_ + kt + kq * 4);
      wsh[kq * 4 + 0][r] = u.x;
      wsh[kq * 4 + 1][r] = u.y;
      wsh[kq * 4 + 2][r] = u.z;
      wsh[kq * 4 + 3][r] = u.w;
    }
    __syncthreads();
    #pragma unroll
    for (int k = 0; k < BKK; ++k) {
      float4 a0 = *(const float4*)&xs[k][ty * 4];
      float4 a1 = *(const float4*)&xs[k][ty * 4 + 64];
      float4 b0 = *(const float4*)&wsh[k][tx * 4];
      float4 b1 = *(const float4*)&wsh[k][tx * 4 + 64];
      float ar[8] = {a0.x, a0.y, a0.z, a0.w, a1.x, a1.y, a1.z, a1.w};
      float br[8] = {b0.x, b0.y, b0.z, b0.w, b1.x, b1.y, b1.z, b1.w};
      #pragma unroll
      for (int i = 0; i < 8; ++i)
        #pragma unroll
        for (int j = 0; j < 8; ++j)
          acc[i][j] = fmaf(ar[i], br[j], acc[i][j]);
    }
    __syncthreads();
  }

  float xv[8], wv[8];
  int rowidx[8], colidx[8];
  #pragma unroll
  for (int i = 0; i < 8; ++i) {
    rowidx[i] = row0 + ty * 4 + (i & 3) + (i >> 2) * 64;
    xv[i] = xsq[rowidx[i]];
  }
  #pragma unroll
  for (int j = 0; j < 8; ++j) {
    colidx[j] = col0 + tx * 4 + (j & 3) + (j >> 2) * 64;
    wv[j] = wsq[colidx[j]];
  }
  #pragma unroll
  for (int i = 0; i < 8; ++i) {
    unsigned long long best = 0xFFFFFFFFFFFFFFFFULL;
    #pragma unroll
    for (int j = 0; j < 8; ++j) {
      float t2 = xv[i] - 2.0f * acc[i][j];
      float sq = t2 + wv[j];
      float d = sqrtf(fmaxf(sq, 0.0f));
      unsigned long long key =
          ((unsigned long long)__float_as_uint(d) << 32) | (unsigned)colidx[j];
      best = key < best ? key : best;
    }
    #pragma unroll
    for (int off = 1; off < 16; off <<= 1) {
      unsigned long long o = __shfl_xor(best, off, 16);
      best = o < best ? o : best;
    }
    if (tx == 0) atomicMin(&keys[rowidx[i]], best);
  }
}

__global__ void finalize_kernel(const unsigned long long* __restrict__ keys,
                                const float* __restrict__ GT,
                                const float* __restrict__ G,
                                float* __restrict__ out, int useGT) {
  int b = blockIdx.x;
  unsigned h = (unsigned)(keys[b] & 0xFFFFFFFFULL);
  if (threadIdx.x == 0) out[(size_t)B_ * O_ + b] = (float)h;
  if (useGT) {
    const float4* src = (const float4*)(GT + (size_t)h * O_);
    float4* dst = (float4*)(out + (size_t)b * O_);
    for (int i = threadIdx.x; i < O_ / 4; i += blockDim.x) dst[i] = src[i];
  } else {
    for (int o = threadIdx.x; o < O_; o += blockDim.x)
      out[(size_t)b * O_ + o] = G[(size_t)o * H_ + h];
  }
}

// ---------------------------------------------------------------------------
extern "C" void kernel_launch(void* const* d_in, const int* in_sizes, int n_in,
                              void* d_out, int out_size, void* d_ws, size_t ws_size,
                              hipStream_t stream) {
  const float* x = (const float*)d_in[0];
  const float* W = (const float*)d_in[1];
  const float* G = (const float*)d_in[2];
  float* out = (float*)d_out;
  char* ws = (char*)d_ws;

  size_t o_xsq  = 0;                                  // 64 KB
  size_t o_wsq  = o_xsq + 65536;                      // 16 KB
  size_t o_xhi  = o_wsq + 16384;                      // 16 MB
  size_t o_whi  = o_xhi + (size_t)B_ * K_ * 2;        // 4 MB
  size_t o_gm   = o_whi + (size_t)H_ * K_ * 2;        // 16 MB
  size_t o_mk   = o_gm + (size_t)B_ * 256 * 4;        // 8 MB
  size_t o_gt   = o_mk + (size_t)B_ * 256 * 2;        // 8 MB
  size_t need   = o_gt + (size_t)H_ * O_ * 4;

  if (ws_size >= need) {
    float* xsq = (float*)(ws + o_xsq);
    float* wsq = (float*)(ws + o_wsq);
    unsigned short* xhi = (unsigned short*)(ws + o_xhi);
    unsigned short* whi = (unsigned short*)(ws + o_whi);
    float* gm = (float*)(ws + o_gm);
    unsigned short* mk = (unsigned short*)(ws + o_mk);
    float* GT = (float*)(ws + o_gt);

    hipLaunchKernelGGL(prep_all_kernel, dim3(2048 + 512 + 2048), dim3(256), 0, stream,
                       x, W, G, xhi, whi, xsq, wsq, GT);
    hipLaunchKernelGGL(phase1_mfma_kernel, dim3(B_ / 256, H_ / 256), dim3(512), 0, stream,
                       xhi, whi, wsq, xsq, gm, mk);
    hipLaunchKernelGGL(phase2_block_kernel, dim3(B_ / P2_ROWS), dim3(256), 0, stream,
                       gm, mk, x, W, xsq, wsq, GT, out);
    return;
  }

  // Fallback: round-1 exact path
  unsigned long long* keys = (unsigned long long*)ws;
  float* xsq = (float*)(ws + 131072);
  float* wsq = (float*)(ws + 131072 + 65536);
  float* GT = (float*)(ws + 131072 + 65536 + 16384);
  size_t base = 131072 + 65536 + 16384;
  int useGT = ws_size >= base + (size_t)H_ * O_ * 4 ? 1 : 0;

  hipLaunchKernelGGL(init_keys_kernel, dim3(B_ / 256), dim3(256), 0, stream, keys);
  hipLaunchKernelGGL(rowsumsq_kernel, dim3(B_ / 256), dim3(256), 0, stream, x, xsq, B_);
  hipLaunchKernelGGL(rowsumsq_kernel, dim3(H_ / 256), dim3(256), 0, stream, W, wsq, H_);
  if (useGT)
    hipLaunchKernelGGL(transposeG_kernel, dim3(H_ / 32, O_ / 32), dim3(32, 8), 0, stream,
                       G, GT);
  hipLaunchKernelGGL(dist_argmin_kernel, dim3(B_ / BM, H_ / BN), dim3(256), 0, stream,
                     x, W, xsq, wsq, keys);
  hipLaunchKernelGGL(finalize_kernel, dim3(B_), dim3(128), 0, stream, keys, GT, G, out,
                     useGT);
}